// Round 1
// baseline (342.876 us; speedup 1.0000x reference)
//
#include <hip/hip_runtime.h>
#include <hip/hip_bf16.h>

// Trittention, factorized:
//   z[q,h] = sum_{t<=q} Eqk[q,t]*v2[t,h]*G_q[t,h] / sum_{t<=q} Eqk[q,t]*g_q[t]
//   G_q[t,h] = sum_{s<=q} Ekk[s,t]*silu(v1)[s,h]   (prefix over s)
//   g_q[t]   = sum_{s<=q} Ekk[s,t]
// Reduces O(T^3*H) reference contraction to O(T^2*H) per (b,n).

constexpr int Tn = 192;          // sequence length
constexpr int DM = 512;          // d_model
constexpr int NH = 8;            // heads
constexpr int HD = 64;           // head dim
constexpr int TT = Tn * Tn;      // 36864
constexpr int BTH = NH * Tn * HD; // per-batch head-major panel stride (bn indexed)

// ---------------- Kernel 1: fused input projections ----------------
// x[384,512] @ [Wkkq(1536) | Wv1(512) | Wv2(512)], bias, silu on v1,
// scatter to head-major [bn][t][h] layouts.
__global__ __launch_bounds__(256) void k_proj(
    const float* __restrict__ x,
    const float* __restrict__ Wkkq, const float* __restrict__ bkkq,
    const float* __restrict__ Wv1,  const float* __restrict__ bv1,
    const float* __restrict__ Wv2,  const float* __restrict__ bv2,
    float* __restrict__ k1, float* __restrict__ k2, float* __restrict__ qv,
    float* __restrict__ sv1, float* __restrict__ v2o)
{
    __shared__ float xs[16][DM];   // 32 KB
    const int tid  = threadIdx.x;
    const int row0 = blockIdx.x * 16;
    for (int i = tid; i < 16 * DM; i += 256) {
        int r = i >> 9, cc = i & 511;
        xs[r][cc] = x[(row0 + r) * DM + cc];
    }
    __syncthreads();

    const int by = blockIdx.y;
    const float* W; const float* bias; int ldw, cbase, seg;
    if (by < 12)      { W = Wkkq; bias = bkkq; ldw = 1536; cbase = by * 128;        seg = 0; }
    else if (by < 16) { W = Wv1;  bias = bv1;  ldw = 512;  cbase = (by - 12) * 128; seg = 1; }
    else              { W = Wv2;  bias = bv2;  ldw = 512;  cbase = (by - 16) * 128; seg = 2; }

    const int c  = cbase + (tid & 127);   // segment-local output column
    const int rh = tid >> 7;              // 0/1 -> rows rh*8 .. rh*8+7

    float acc[8] = {0.f,0.f,0.f,0.f,0.f,0.f,0.f,0.f};
    for (int k4 = 0; k4 < DM; k4 += 4) {
        const float w0 = W[(k4 + 0) * ldw + c];
        const float w1 = W[(k4 + 1) * ldw + c];
        const float w2 = W[(k4 + 2) * ldw + c];
        const float w3 = W[(k4 + 3) * ldw + c];
#pragma unroll
        for (int r = 0; r < 8; ++r) {
            const float4 xv = *reinterpret_cast<const float4*>(&xs[rh * 8 + r][k4]);
            acc[r] = fmaf(xv.x, w0, acc[r]);
            acc[r] = fmaf(xv.y, w1, acc[r]);
            acc[r] = fmaf(xv.z, w2, acc[r]);
            acc[r] = fmaf(xv.w, w3, acc[r]);
        }
    }

    const float bb = bias[c];
#pragma unroll
    for (int r = 0; r < 8; ++r) {
        const int grow = row0 + rh * 8 + r;
        const int b = grow / Tn, t = grow % Tn;
        float val = acc[r] + bb;
        if (seg == 0) {
            const int third = c >> 9, nh = c & 511, n = nh >> 6, h = nh & 63;
            float* dst = (third == 0) ? k1 : (third == 1) ? k2 : qv;
            dst[((b * NH + n) * Tn + t) * HD + h] = val;
        } else {
            const int n = c >> 6, h = c & 63;
            if (seg == 1) {
                const float s = val / (1.f + __expf(-val));   // silu
                sv1[((b * NH + n) * Tn + t) * HD + h] = s;
            } else {
                v2o[((b * NH + n) * Tn + t) * HD + h] = val;
            }
        }
    }
}

// ---------------- Kernel 2: exp(score/64) tables ----------------
// mat==0: Ekk[s,t] = exp(k1[s].k2[t]/64);  mat==1: Eqk[q,t] = exp(qv[q].k2[t]/64)
__global__ __launch_bounds__(256) void k_scores(
    const float* __restrict__ k1, const float* __restrict__ k2,
    const float* __restrict__ qv,
    float* __restrict__ Ekk, float* __restrict__ Eqk)
{
    const int bn  = blockIdx.z;
    const int mat = blockIdx.y;
    const int st  = blockIdx.x / 6, tt = blockIdx.x % 6;
    const float* A  = ((mat == 0) ? k1 : qv) + bn * Tn * HD;
    const float* Bm = k2 + bn * Tn * HD;
    float* E = ((mat == 0) ? Ekk : Eqk) + bn * TT;

    __shared__ float As[32][65], Bs[32][65];
    const int tid = threadIdx.x;
    for (int i = tid; i < 32 * 64; i += 256) {
        const int r = i >> 6, h = i & 63;
        As[r][h] = A[(st * 32 + r) * HD + h];
        Bs[r][h] = Bm[(tt * 32 + r) * HD + h];
    }
    __syncthreads();

    const int tx = tid & 15, ty = tid >> 4;
    const int r0 = ty * 2, c0 = tx * 2;
    float a00 = 0.f, a01 = 0.f, a10 = 0.f, a11 = 0.f;
#pragma unroll
    for (int h = 0; h < 64; ++h) {
        const float ar0 = As[r0][h], ar1 = As[r0 + 1][h];
        const float bc0 = Bs[c0][h], bc1 = Bs[c0 + 1][h];
        a00 = fmaf(ar0, bc0, a00); a01 = fmaf(ar0, bc1, a01);
        a10 = fmaf(ar1, bc0, a10); a11 = fmaf(ar1, bc1, a11);
    }
    constexpr float sc = 1.f / 64.f;
    const int gr = st * 32 + r0, gc = tt * 32 + c0;
    E[(gr)     * Tn + gc]     = __expf(a00 * sc);
    E[(gr)     * Tn + gc + 1] = __expf(a01 * sc);
    E[(gr + 1) * Tn + gc]     = __expf(a10 * sc);
    E[(gr + 1) * Tn + gc + 1] = __expf(a11 * sc);
}

// ---------------- Kernel 3: prefix-factorized attention ----------------
// One block per (bn, q-tile of 12). Thread (tg,h) owns t in [48*tg, 48*tg+48)
// for its h: G/g prefix state lives entirely in registers, no LDS, no barriers.
__global__ __launch_bounds__(256) void k_attn(
    const float* __restrict__ Ekk, const float* __restrict__ Eqk,
    const float* __restrict__ sv1, const float* __restrict__ v2,
    float* __restrict__ z)
{
    const int bid  = blockIdx.x;
    const int bn   = bid >> 4;
    const int tile = bid & 15;
    const int q0   = tile * 12;
    const int tid  = threadIdx.x;
    const int tg   = tid & 3, h = tid >> 2;
    const int b = bn >> 3, n = bn & 7;

    const float* ekk = Ekk + bn * TT;
    const float* eqk = Eqk + bn * TT;
    const float* s1  = sv1 + bn * Tn * HD;
    const float* vv  = v2  + bn * Tn * HD;

    float G[48], g[48];
#pragma unroll
    for (int j = 0; j < 48; ++j) { G[j] = 0.f; g[j] = 0.f; }

    const int t0 = tg * 48;

    // prefix base: s < q0
    for (int s = 0; s < q0; ++s) {
        const float a = s1[s * HD + h];
        const float* ek = ekk + s * Tn + t0;
#pragma unroll
        for (int jj = 0; jj < 12; ++jj) {
            const float4 ev = *reinterpret_cast<const float4*>(&ek[4 * jj]);
            G[4*jj+0] = fmaf(ev.x, a, G[4*jj+0]); g[4*jj+0] += ev.x;
            G[4*jj+1] = fmaf(ev.y, a, G[4*jj+1]); g[4*jj+1] += ev.y;
            G[4*jj+2] = fmaf(ev.z, a, G[4*jj+2]); g[4*jj+2] += ev.z;
            G[4*jj+3] = fmaf(ev.w, a, G[4*jj+3]); g[4*jj+3] += ev.w;
        }
    }

    for (int q = q0; q < q0 + 12; ++q) {
        { // add row s = q to the prefix
            const float a = s1[q * HD + h];
            const float* ek = ekk + q * Tn + t0;
#pragma unroll
            for (int jj = 0; jj < 12; ++jj) {
                const float4 ev = *reinterpret_cast<const float4*>(&ek[4 * jj]);
                G[4*jj+0] = fmaf(ev.x, a, G[4*jj+0]); g[4*jj+0] += ev.x;
                G[4*jj+1] = fmaf(ev.y, a, G[4*jj+1]); g[4*jj+1] += ev.y;
                G[4*jj+2] = fmaf(ev.z, a, G[4*jj+2]); g[4*jj+2] += ev.z;
                G[4*jj+3] = fmaf(ev.w, a, G[4*jj+3]); g[4*jj+3] += ev.w;
            }
        }
        // z[q,h] = sum_{t<=q} eqk*v2*G / sum_{t<=q} eqk*g
        const float* eq = eqk + q * Tn;
        float zp = 0.f, Zp = 0.f;
#pragma unroll
        for (int j = 0; j < 48; ++j) {
            const int t = t0 + j;
            if (t <= q) {
                const float e = eq[t];
                const float v = vv[t * HD + h];
                zp = fmaf(e * v, G[j], zp);
                Zp = fmaf(e, g[j], Zp);
            }
        }
        zp += __shfl_xor(zp, 1); zp += __shfl_xor(zp, 2);
        Zp += __shfl_xor(Zp, 1); Zp += __shfl_xor(Zp, 2);
        if (tg == 0) z[((b * Tn + q) * NH + n) * HD + h] = zp / Zp;
    }
}

// ---------------- Kernel 4: output projection ----------------
__global__ __launch_bounds__(256) void k_out(
    const float* __restrict__ z, const float* __restrict__ Wout,
    const float* __restrict__ bout, float* __restrict__ out)
{
    __shared__ float zs[16][DM];
    const int tid  = threadIdx.x;
    const int row0 = blockIdx.x * 16;
    for (int i = tid; i < 16 * DM; i += 256) {
        const int r = i >> 9, cc = i & 511;
        zs[r][cc] = z[(row0 + r) * DM + cc];
    }
    __syncthreads();

    const int c  = blockIdx.y * 128 + (tid & 127);
    const int rh = tid >> 7;
    float acc[8] = {0.f,0.f,0.f,0.f,0.f,0.f,0.f,0.f};
    for (int k4 = 0; k4 < DM; k4 += 4) {
        const float w0 = Wout[(k4 + 0) * DM + c];
        const float w1 = Wout[(k4 + 1) * DM + c];
        const float w2 = Wout[(k4 + 2) * DM + c];
        const float w3 = Wout[(k4 + 3) * DM + c];
#pragma unroll
        for (int r = 0; r < 8; ++r) {
            const float4 xv = *reinterpret_cast<const float4*>(&zs[rh * 8 + r][k4]);
            acc[r] = fmaf(xv.x, w0, acc[r]);
            acc[r] = fmaf(xv.y, w1, acc[r]);
            acc[r] = fmaf(xv.z, w2, acc[r]);
            acc[r] = fmaf(xv.w, w3, acc[r]);
        }
    }
    const float bb = bout[c];
#pragma unroll
    for (int r = 0; r < 8; ++r)
        out[(row0 + rh * 8 + r) * DM + c] = acc[r] + bb;
}

extern "C" void kernel_launch(void* const* d_in, const int* in_sizes, int n_in,
                              void* d_out, int out_size, void* d_ws, size_t ws_size,
                              hipStream_t stream) {
    const float* x    = (const float*)d_in[0];
    const float* Wkkq = (const float*)d_in[1];
    const float* bkkq = (const float*)d_in[2];
    const float* Wv1  = (const float*)d_in[3];
    const float* bv1  = (const float*)d_in[4];
    const float* Wv2  = (const float*)d_in[5];
    const float* bv2  = (const float*)d_in[6];
    const float* Wout = (const float*)d_in[7];
    const float* bout = (const float*)d_in[8];
    float* out = (float*)d_out;

    // workspace partition (floats): 6 panels of 196608 + 2 tables of 589824 = 9.44 MB
    float* ws  = (float*)d_ws;
    float* k1  = ws;
    float* k2  = k1  + 196608;
    float* qv  = k2  + 196608;
    float* sv1 = qv  + 196608;
    float* v2  = sv1 + 196608;
    float* z   = v2  + 196608;
    float* Ekk = z   + 196608;
    float* Eqk = Ekk + 589824;

    k_proj  <<<dim3(24, 20),    256, 0, stream>>>(x, Wkkq, bkkq, Wv1, bv1, Wv2, bv2,
                                                  k1, k2, qv, sv1, v2);
    k_scores<<<dim3(36, 2, 16), 256, 0, stream>>>(k1, k2, qv, Ekk, Eqk);
    k_attn  <<<dim3(256),       256, 0, stream>>>(Ekk, Eqk, sv1, v2, z);
    k_out   <<<dim3(24, 4),     256, 0, stream>>>(z, Wout, bout, out);
}

// Round 2
// 181.135 us; speedup vs baseline: 1.8929x; 1.8929x over previous
//
#include <hip/hip_runtime.h>
#include <hip/hip_bf16.h>

// Trittention, factorized:
//   z[q,h] = sum_{t<=q} Eqk[q,t]*v2[t,h]*G_q[t,h] / sum_{t<=q} Eqk[q,t]*g_q[t]
//   G_q[t,h] = sum_{s<=q} Ekk[s,t]*silu(v1)[s,h]   (prefix over s)
//   g_q[t]   = sum_{s<=q} Ekk[s,t]
// R1: prefix via reduce-then-scan checkpoints (8 chunks of 24 rows) to kill
// the 8.5x prefix recompute and the 1-wave/SIMD latency stall of R0.

constexpr int Tn = 192;          // sequence length
constexpr int DM = 512;          // d_model
constexpr int NH = 8;            // heads
constexpr int HD = 64;           // head dim
constexpr int TT = Tn * Tn;      // 36864
constexpr int NC = 8;            // checkpoint chunks
constexpr int CS = 24;           // s-rows per chunk

// ---------------- Kernel 1: fused input projections ----------------
__global__ __launch_bounds__(256) void k_proj(
    const float* __restrict__ x,
    const float* __restrict__ Wkkq, const float* __restrict__ bkkq,
    const float* __restrict__ Wv1,  const float* __restrict__ bv1,
    const float* __restrict__ Wv2,  const float* __restrict__ bv2,
    float* __restrict__ k1, float* __restrict__ k2, float* __restrict__ qv,
    float* __restrict__ sv1, float* __restrict__ v2o)
{
    __shared__ float xs[16][DM];   // 32 KB
    const int tid  = threadIdx.x;
    const int row0 = blockIdx.x * 16;
    for (int i = tid; i < 16 * DM; i += 256) {
        int r = i >> 9, cc = i & 511;
        xs[r][cc] = x[(row0 + r) * DM + cc];
    }
    __syncthreads();

    const int by = blockIdx.y;
    const float* W; const float* bias; int ldw, cbase, seg;
    if (by < 12)      { W = Wkkq; bias = bkkq; ldw = 1536; cbase = by * 128;        seg = 0; }
    else if (by < 16) { W = Wv1;  bias = bv1;  ldw = 512;  cbase = (by - 12) * 128; seg = 1; }
    else              { W = Wv2;  bias = bv2;  ldw = 512;  cbase = (by - 16) * 128; seg = 2; }

    const int c  = cbase + (tid & 127);
    const int rh = tid >> 7;

    float acc[8] = {0.f,0.f,0.f,0.f,0.f,0.f,0.f,0.f};
    for (int k4 = 0; k4 < DM; k4 += 4) {
        const float w0 = W[(k4 + 0) * ldw + c];
        const float w1 = W[(k4 + 1) * ldw + c];
        const float w2 = W[(k4 + 2) * ldw + c];
        const float w3 = W[(k4 + 3) * ldw + c];
#pragma unroll
        for (int r = 0; r < 8; ++r) {
            const float4 xv = *reinterpret_cast<const float4*>(&xs[rh * 8 + r][k4]);
            acc[r] = fmaf(xv.x, w0, acc[r]);
            acc[r] = fmaf(xv.y, w1, acc[r]);
            acc[r] = fmaf(xv.z, w2, acc[r]);
            acc[r] = fmaf(xv.w, w3, acc[r]);
        }
    }

    const float bb = bias[c];
#pragma unroll
    for (int r = 0; r < 8; ++r) {
        const int grow = row0 + rh * 8 + r;
        const int b = grow / Tn, t = grow % Tn;
        float val = acc[r] + bb;
        if (seg == 0) {
            const int third = c >> 9, nh = c & 511, n = nh >> 6, h = nh & 63;
            float* dst = (third == 0) ? k1 : (third == 1) ? k2 : qv;
            dst[((b * NH + n) * Tn + t) * HD + h] = val;
        } else {
            const int n = c >> 6, h = c & 63;
            if (seg == 1) {
                const float s = val / (1.f + __expf(-val));   // silu
                sv1[((b * NH + n) * Tn + t) * HD + h] = s;
            } else {
                v2o[((b * NH + n) * Tn + t) * HD + h] = val;
            }
        }
    }
}

// ---------------- Kernel 2: exp(score/64) tables ----------------
__global__ __launch_bounds__(256) void k_scores(
    const float* __restrict__ k1, const float* __restrict__ k2,
    const float* __restrict__ qv,
    float* __restrict__ Ekk, float* __restrict__ Eqk)
{
    const int bn  = blockIdx.z;
    const int mat = blockIdx.y;
    const int st  = blockIdx.x / 6, tt = blockIdx.x % 6;
    const float* A  = ((mat == 0) ? k1 : qv) + bn * Tn * HD;
    const float* Bm = k2 + bn * Tn * HD;
    float* E = ((mat == 0) ? Ekk : Eqk) + bn * TT;

    __shared__ float As[32][65], Bs[32][65];
    const int tid = threadIdx.x;
    for (int i = tid; i < 32 * 64; i += 256) {
        const int r = i >> 6, h = i & 63;
        As[r][h] = A[(st * 32 + r) * HD + h];
        Bs[r][h] = Bm[(tt * 32 + r) * HD + h];
    }
    __syncthreads();

    const int tx = tid & 15, ty = tid >> 4;
    const int r0 = ty * 2, c0 = tx * 2;
    float a00 = 0.f, a01 = 0.f, a10 = 0.f, a11 = 0.f;
#pragma unroll
    for (int h = 0; h < 64; ++h) {
        const float ar0 = As[r0][h], ar1 = As[r0 + 1][h];
        const float bc0 = Bs[c0][h], bc1 = Bs[c0 + 1][h];
        a00 = fmaf(ar0, bc0, a00); a01 = fmaf(ar0, bc1, a01);
        a10 = fmaf(ar1, bc0, a10); a11 = fmaf(ar1, bc1, a11);
    }
    constexpr float sc = 1.f / 64.f;
    const int gr = st * 32 + r0, gc = tt * 32 + c0;
    E[(gr)     * Tn + gc]     = __expf(a00 * sc);
    E[(gr)     * Tn + gc + 1] = __expf(a01 * sc);
    E[(gr + 1) * Tn + gc]     = __expf(a10 * sc);
    E[(gr + 1) * Tn + gc + 1] = __expf(a11 * sc);
}

// ---------------- Kernel 3a: per-chunk partial sums ----------------
// P[bn][c][h][t] = sum_{s in chunk c} Ekk[s,t]*sv1[s,h]
__global__ __launch_bounds__(256) void k_partial(
    const float* __restrict__ Ekk, const float* __restrict__ sv1,
    float* __restrict__ P)
{
    const int hhalf = blockIdx.x;   // 0..1
    const int c     = blockIdx.y;   // 0..7
    const int bn    = blockIdx.z;   // 0..15
    const int tid   = threadIdx.x;
    const int tg    = tid & 7;          // 8 t-groups of 24
    const int h     = hhalf * 32 + (tid >> 3);
    const int t0    = tg * 24;
    const float* ekk = Ekk + bn * TT;
    const float* s1  = sv1 + bn * Tn * HD;

    float G[24];
#pragma unroll
    for (int j = 0; j < 24; ++j) G[j] = 0.f;

    for (int s = c * CS; s < c * CS + CS; ++s) {
        const float a = s1[s * HD + h];
        const float* ek = ekk + s * Tn + t0;
#pragma unroll
        for (int jj = 0; jj < 6; ++jj) {
            const float4 ev = *reinterpret_cast<const float4*>(&ek[4 * jj]);
            G[4*jj+0] = fmaf(ev.x, a, G[4*jj+0]);
            G[4*jj+1] = fmaf(ev.y, a, G[4*jj+1]);
            G[4*jj+2] = fmaf(ev.z, a, G[4*jj+2]);
            G[4*jj+3] = fmaf(ev.w, a, G[4*jj+3]);
        }
    }
    float* dst = P + ((bn * NC + c) * HD + h) * Tn + t0;
#pragma unroll
    for (int jj = 0; jj < 6; ++jj)
        *reinterpret_cast<float4*>(&dst[4 * jj]) =
            make_float4(G[4*jj], G[4*jj+1], G[4*jj+2], G[4*jj+3]);
}

// ---------------- Kernel 3b: in-place inclusive scan over chunks ----------------
__global__ __launch_bounds__(256) void k_scan(float* __restrict__ P)
{
    const int bn  = blockIdx.y;
    const int off = blockIdx.x * 256 + threadIdx.x;   // 0..12287
    float* base = P + bn * NC * HD * Tn;
    float run = base[off];
    for (int c = 1; c < NC; ++c) {
        run += base[c * HD * Tn + off];
        base[c * HD * Tn + off] = run;
    }
}

// ---------------- Kernel 3c: cumulative column sums of Ekk (g checkpoints) ----
__global__ __launch_bounds__(192) void k_gcum(
    const float* __restrict__ Ekk, float* __restrict__ gC)
{
    const int bn = blockIdx.x;
    const int t  = threadIdx.x;
    const float* ekk = Ekk + bn * TT;
    float sum = 0.f;
    for (int c = 0; c < NC; ++c) {
#pragma unroll
        for (int i = 0; i < CS; ++i)
            sum += ekk[(c * CS + i) * Tn + t];
        gC[(bn * NC + c) * Tn + t] = sum;
    }
}

// ---------------- Kernel 3d: attention from checkpoints ----------------
// block = (hq, qtile, bn); thread (tg in 16, hh in 16): t-range 12, one h.
__global__ __launch_bounds__(256) void k_attn2(
    const float* __restrict__ Ekk, const float* __restrict__ Eqk,
    const float* __restrict__ sv1, const float* __restrict__ v2,
    const float* __restrict__ P,   const float* __restrict__ gC,
    float* __restrict__ z)
{
    const int hq = blockIdx.x;     // 0..3
    const int qt = blockIdx.y;     // 0..15
    const int bn = blockIdx.z;     // 0..15
    const int b = bn >> 3, n = bn & 7;
    const int tid = threadIdx.x;
    const int tg  = tid & 15;
    const int hh  = tid >> 4;
    const int h   = hq * 16 + hh;
    const int t0  = tg * 12;
    const int q0  = qt * 12;
    const int cb  = q0 / CS;       // chunk containing q0; base ckpt = cb-1

    const float* ekk = Ekk + bn * TT;
    const float* eqk = Eqk + bn * TT;
    const float* s1  = sv1 + bn * Tn * HD;
    const float* vv  = v2  + bn * Tn * HD;

    float G[12], g[12];
    if (cb > 0) {
        const float* pb = P  + ((bn * NC + (cb - 1)) * HD + h) * Tn + t0;
        const float* gb = gC + (bn * NC + (cb - 1)) * Tn + t0;
#pragma unroll
        for (int jj = 0; jj < 3; ++jj) {
            const float4 pv = *reinterpret_cast<const float4*>(&pb[4 * jj]);
            G[4*jj+0] = pv.x; G[4*jj+1] = pv.y; G[4*jj+2] = pv.z; G[4*jj+3] = pv.w;
            const float4 gv = *reinterpret_cast<const float4*>(&gb[4 * jj]);
            g[4*jj+0] = gv.x; g[4*jj+1] = gv.y; g[4*jj+2] = gv.z; g[4*jj+3] = gv.w;
        }
    } else {
#pragma unroll
        for (int j = 0; j < 12; ++j) { G[j] = 0.f; g[j] = 0.f; }
    }

    // hoist v2 slice (q-independent)
    float vvr[12];
#pragma unroll
    for (int j = 0; j < 12; ++j) vvr[j] = vv[(t0 + j) * HD + h];

    // replay rows [CS*cb, q0)
    for (int s = CS * cb; s < q0; ++s) {
        const float a = s1[s * HD + h];
        const float* ek = ekk + s * Tn + t0;
#pragma unroll
        for (int jj = 0; jj < 3; ++jj) {
            const float4 ev = *reinterpret_cast<const float4*>(&ek[4 * jj]);
            G[4*jj+0] = fmaf(ev.x, a, G[4*jj+0]); g[4*jj+0] += ev.x;
            G[4*jj+1] = fmaf(ev.y, a, G[4*jj+1]); g[4*jj+1] += ev.y;
            G[4*jj+2] = fmaf(ev.z, a, G[4*jj+2]); g[4*jj+2] += ev.z;
            G[4*jj+3] = fmaf(ev.w, a, G[4*jj+3]); g[4*jj+3] += ev.w;
        }
    }

    for (int q = q0; q < q0 + 12; ++q) {
        { // fold in row s = q
            const float a = s1[q * HD + h];
            const float* ek = ekk + q * Tn + t0;
#pragma unroll
            for (int jj = 0; jj < 3; ++jj) {
                const float4 ev = *reinterpret_cast<const float4*>(&ek[4 * jj]);
                G[4*jj+0] = fmaf(ev.x, a, G[4*jj+0]); g[4*jj+0] += ev.x;
                G[4*jj+1] = fmaf(ev.y, a, G[4*jj+1]); g[4*jj+1] += ev.y;
                G[4*jj+2] = fmaf(ev.z, a, G[4*jj+2]); g[4*jj+2] += ev.z;
                G[4*jj+3] = fmaf(ev.w, a, G[4*jj+3]); g[4*jj+3] += ev.w;
            }
        }
        const float* eq = eqk + q * Tn + t0;
        float zp = 0.f, Zp = 0.f;
#pragma unroll
        for (int jj = 0; jj < 3; ++jj) {
            const float4 ev = *reinterpret_cast<const float4*>(&eq[4 * jj]);
            const float e0 = (t0 + 4*jj + 0 <= q) ? ev.x : 0.f;
            const float e1 = (t0 + 4*jj + 1 <= q) ? ev.y : 0.f;
            const float e2 = (t0 + 4*jj + 2 <= q) ? ev.z : 0.f;
            const float e3 = (t0 + 4*jj + 3 <= q) ? ev.w : 0.f;
            zp = fmaf(e0 * vvr[4*jj+0], G[4*jj+0], zp); Zp = fmaf(e0, g[4*jj+0], Zp);
            zp = fmaf(e1 * vvr[4*jj+1], G[4*jj+1], zp); Zp = fmaf(e1, g[4*jj+1], Zp);
            zp = fmaf(e2 * vvr[4*jj+2], G[4*jj+2], zp); Zp = fmaf(e2, g[4*jj+2], Zp);
            zp = fmaf(e3 * vvr[4*jj+3], G[4*jj+3], zp); Zp = fmaf(e3, g[4*jj+3], Zp);
        }
        zp += __shfl_xor(zp, 1); zp += __shfl_xor(zp, 2);
        zp += __shfl_xor(zp, 4); zp += __shfl_xor(zp, 8);
        Zp += __shfl_xor(Zp, 1); Zp += __shfl_xor(Zp, 2);
        Zp += __shfl_xor(Zp, 4); Zp += __shfl_xor(Zp, 8);
        if (tg == 0) z[((b * Tn + q) * NH + n) * HD + h] = zp / Zp;
    }
}

// ---------------- Kernel 4: output projection ----------------
__global__ __launch_bounds__(256) void k_out(
    const float* __restrict__ z, const float* __restrict__ Wout,
    const float* __restrict__ bout, float* __restrict__ out)
{
    __shared__ float zs[16][DM];
    const int tid  = threadIdx.x;
    const int row0 = blockIdx.x * 16;
    for (int i = tid; i < 16 * DM; i += 256) {
        const int r = i >> 9, cc = i & 511;
        zs[r][cc] = z[(row0 + r) * DM + cc];
    }
    __syncthreads();

    const int c  = blockIdx.y * 128 + (tid & 127);
    const int rh = tid >> 7;
    float acc[8] = {0.f,0.f,0.f,0.f,0.f,0.f,0.f,0.f};
    for (int k4 = 0; k4 < DM; k4 += 4) {
        const float w0 = Wout[(k4 + 0) * DM + c];
        const float w1 = Wout[(k4 + 1) * DM + c];
        const float w2 = Wout[(k4 + 2) * DM + c];
        const float w3 = Wout[(k4 + 3) * DM + c];
#pragma unroll
        for (int r = 0; r < 8; ++r) {
            const float4 xv = *reinterpret_cast<const float4*>(&zs[rh * 8 + r][k4]);
            acc[r] = fmaf(xv.x, w0, acc[r]);
            acc[r] = fmaf(xv.y, w1, acc[r]);
            acc[r] = fmaf(xv.z, w2, acc[r]);
            acc[r] = fmaf(xv.w, w3, acc[r]);
        }
    }
    const float bb = bout[c];
#pragma unroll
    for (int r = 0; r < 8; ++r)
        out[(row0 + rh * 8 + r) * DM + c] = acc[r] + bb;
}

extern "C" void kernel_launch(void* const* d_in, const int* in_sizes, int n_in,
                              void* d_out, int out_size, void* d_ws, size_t ws_size,
                              hipStream_t stream) {
    const float* x    = (const float*)d_in[0];
    const float* Wkkq = (const float*)d_in[1];
    const float* bkkq = (const float*)d_in[2];
    const float* Wv1  = (const float*)d_in[3];
    const float* bv1  = (const float*)d_in[4];
    const float* Wv2  = (const float*)d_in[5];
    const float* bv2  = (const float*)d_in[6];
    const float* Wout = (const float*)d_in[7];
    const float* bout = (const float*)d_in[8];
    float* out = (float*)d_out;

    // ws partition (floats): 6 panels 196608 + 2 tables 589824 + P 1572864 + gC 24576
    float* ws  = (float*)d_ws;
    float* k1  = ws;
    float* k2  = k1  + 196608;
    float* qv  = k2  + 196608;
    float* sv1 = qv  + 196608;
    float* v2  = sv1 + 196608;
    float* z   = v2  + 196608;
    float* Ekk = z   + 196608;
    float* Eqk = Ekk + 589824;
    float* P   = Eqk + 589824;
    float* gC  = P   + 1572864;

    k_proj   <<<dim3(24, 20),    256, 0, stream>>>(x, Wkkq, bkkq, Wv1, bv1, Wv2, bv2,
                                                   k1, k2, qv, sv1, v2);
    k_scores <<<dim3(36, 2, 16), 256, 0, stream>>>(k1, k2, qv, Ekk, Eqk);
    k_partial<<<dim3(2, 8, 16),  256, 0, stream>>>(Ekk, sv1, P);
    k_gcum   <<<dim3(16),        192, 0, stream>>>(Ekk, gC);
    k_scan   <<<dim3(48, 16),    256, 0, stream>>>(P);
    k_attn2  <<<dim3(4, 16, 16), 256, 0, stream>>>(Ekk, Eqk, sv1, v2, P, gC, z);
    k_out    <<<dim3(24, 4),     256, 0, stream>>>(z, Wout, bout, out);
}

// Round 5
// 108.571 us; speedup vs baseline: 3.1581x; 1.6684x over previous
//
#include <hip/hip_runtime.h>
#include <hip/hip_bf16.h>

// Trittention, factorized:
//   z[q,h] = sum_{t<=q} Eqk[q,t]*v2[t,h]*G_q[t,h] / sum_{t<=q} Eqk[q,t]*g_q[t]
//   G_q[t,h] = sum_{s<=q} Ekk[s,t]*silu(v1)[s,h]   (prefix over s)
// R2-R4: projection GEMMs -> MFMA with error-compensated bf16x3 split
// (A ~ Ahi+Alo; A.B = Ahi.Bhi + Ahi.Blo + Alo.Bhi, fp32 accum; rel err ~2^-16).

constexpr int Tn = 192;
constexpr int DM = 512;
constexpr int NH = 8;
constexpr int HD = 64;
constexpr int TT = Tn * Tn;
constexpr int NC = 8;            // checkpoint chunks
constexpr int CS = 24;           // s-rows per chunk

typedef __bf16 bf16_t;
typedef bf16_t bf16x8 __attribute__((ext_vector_type(8)));
typedef bf16_t bf16x4 __attribute__((ext_vector_type(4)));
typedef float  f32x4  __attribute__((ext_vector_type(4)));

struct bf16pair { bf16_t h, l; };
__device__ __forceinline__ bf16pair split_bf16(float v) {
    bf16pair r;
    r.h = (bf16_t)v;
    r.l = (bf16_t)(v - (float)r.h);
    return r;
}

// ---------------- Kernel 0: convert x + transpose-convert weights ----------
// Weights W[K][N] fp32 -> Wt_hi/Wt_lo [N][K=512] bf16. x -> xhi/xlo (same layout).
__global__ __launch_bounds__(256) void k_convert(
    const float* __restrict__ x,    const float* __restrict__ Wkkq,
    const float* __restrict__ Wv1,  const float* __restrict__ Wv2,
    const float* __restrict__ Wout,
    bf16_t* __restrict__ xh,    bf16_t* __restrict__ xl,
    bf16_t* __restrict__ wkkqh, bf16_t* __restrict__ wkkql,
    bf16_t* __restrict__ wv1h,  bf16_t* __restrict__ wv1l,
    bf16_t* __restrict__ wv2h,  bf16_t* __restrict__ wv2l,
    bf16_t* __restrict__ wouth, bf16_t* __restrict__ woutl)
{
    const int bid = blockIdx.x;
    const int tid = threadIdx.x;

    if (bid >= 1536) {   // x path: elementwise convert
        const int idx = (bid - 1536) * 1024 + tid * 4;
        const float4 v = *reinterpret_cast<const float4*>(&x[idx]);
        bf16x4 hv, lv;
        bf16pair p0 = split_bf16(v.x), p1 = split_bf16(v.y);
        bf16pair p2 = split_bf16(v.z), p3 = split_bf16(v.w);
        hv[0] = p0.h; lv[0] = p0.l; hv[1] = p1.h; lv[1] = p1.l;
        hv[2] = p2.h; lv[2] = p2.l; hv[3] = p3.h; lv[3] = p3.l;
        *reinterpret_cast<bf16x4*>(&xh[idx]) = hv;
        *reinterpret_cast<bf16x4*>(&xl[idx]) = lv;
        return;
    }

    const float* src; bf16_t* dh; bf16_t* dl; int N, lb;
    if (bid < 768)       { src = Wkkq; dh = wkkqh; dl = wkkql; N = 1536; lb = bid; }
    else if (bid < 1024) { src = Wv1;  dh = wv1h;  dl = wv1l;  N = 512;  lb = bid - 768; }
    else if (bid < 1280) { src = Wv2;  dh = wv2h;  dl = wv2l;  N = 512;  lb = bid - 1024; }
    else                 { src = Wout; dh = wouth; dl = woutl; N = 512;  lb = bid - 1280; }

    const int ntn = N >> 5;
    const int k0 = (lb / ntn) * 32, n0 = (lb % ntn) * 32;

    __shared__ float T[32][33];
    const int r = tid >> 3, c4 = (tid & 7) * 4;
    const float4 v = *reinterpret_cast<const float4*>(&src[(k0 + r) * N + n0 + c4]);
    T[r][c4] = v.x; T[r][c4 + 1] = v.y; T[r][c4 + 2] = v.z; T[r][c4 + 3] = v.w;
    __syncthreads();

    const int nr = tid >> 3, kc4 = (tid & 7) * 4;
    bf16x4 hv, lv;
#pragma unroll
    for (int i = 0; i < 4; ++i) {
        bf16pair p = split_bf16(T[kc4 + i][nr]);
        hv[i] = p.h; lv[i] = p.l;
    }
    *reinterpret_cast<bf16x4*>(&dh[(n0 + nr) * DM + k0 + kc4]) = hv;
    *reinterpret_cast<bf16x4*>(&dl[(n0 + nr) * DM + k0 + kc4]) = lv;
}

// ---------------- Kernel 1: MFMA projection GEMM ----------------
// [384x512] @ [512x2560] (cols: 0-1535 Wkkq -> k1/k2/qv, 1536-2047 Wv1 -> silu
// -> sv1, 2048-2559 Wv2 -> v2). 64x64 tile, 4 waves, frags direct from global.
__global__ __launch_bounds__(256) void k_projm(
    const bf16_t* __restrict__ xh,    const bf16_t* __restrict__ xl,
    const bf16_t* __restrict__ wkkqh, const bf16_t* __restrict__ wkkql,
    const bf16_t* __restrict__ wv1h,  const bf16_t* __restrict__ wv1l,
    const bf16_t* __restrict__ wv2h,  const bf16_t* __restrict__ wv2l,
    const float* __restrict__ bkkq, const float* __restrict__ bv1,
    const float* __restrict__ bv2,
    float* __restrict__ k1, float* __restrict__ k2, float* __restrict__ qv,
    float* __restrict__ sv1, float* __restrict__ v2o)
{
    const int bx = blockIdx.x, by = blockIdx.y;
    const int tid = threadIdx.x;
    const int w = tid >> 6, lane = tid & 63;
    const int wm = w >> 1, wn = w & 1;
    const int m0 = by * 64 + wm * 32;
    const int ncol0 = bx * 64 + wn * 32;

    const bf16_t *Bh, *Bl; int nloc0;
    if (bx < 24)      { Bh = wkkqh; Bl = wkkql; nloc0 = ncol0; }
    else if (bx < 32) { Bh = wv1h;  Bl = wv1l;  nloc0 = ncol0 - 1536; }
    else              { Bh = wv2h;  Bl = wv2l;  nloc0 = ncol0 - 2048; }

    const int lr = lane & 15, lk = (lane >> 4) * 8;

    const f32x4 z4 = {0.f, 0.f, 0.f, 0.f};
    f32x4 acc[2][2] = {{z4, z4}, {z4, z4}};

#pragma unroll 2
    for (int ks = 0; ks < 16; ++ks) {
        const int ko = ks * 32 + lk;
        bf16x8 ah[2], al[2], bh[2], bl[2];
#pragma unroll
        for (int mi = 0; mi < 2; ++mi) {
            const int row = m0 + mi * 16 + lr;
            ah[mi] = *reinterpret_cast<const bf16x8*>(&xh[row * DM + ko]);
            al[mi] = *reinterpret_cast<const bf16x8*>(&xl[row * DM + ko]);
        }
#pragma unroll
        for (int ni = 0; ni < 2; ++ni) {
            const int nrow = nloc0 + ni * 16 + lr;
            bh[ni] = *reinterpret_cast<const bf16x8*>(&Bh[nrow * DM + ko]);
            bl[ni] = *reinterpret_cast<const bf16x8*>(&Bl[nrow * DM + ko]);
        }
#pragma unroll
        for (int mi = 0; mi < 2; ++mi)
#pragma unroll
            for (int ni = 0; ni < 2; ++ni) {
                acc[mi][ni] = __builtin_amdgcn_mfma_f32_16x16x32_bf16(ah[mi], bh[ni], acc[mi][ni], 0, 0, 0);
                acc[mi][ni] = __builtin_amdgcn_mfma_f32_16x16x32_bf16(ah[mi], bl[ni], acc[mi][ni], 0, 0, 0);
                acc[mi][ni] = __builtin_amdgcn_mfma_f32_16x16x32_bf16(al[mi], bh[ni], acc[mi][ni], 0, 0, 0);
            }
    }

#pragma unroll
    for (int mi = 0; mi < 2; ++mi)
#pragma unroll
        for (int ni = 0; ni < 2; ++ni)
#pragma unroll
            for (int r = 0; r < 4; ++r) {
                const int row = m0 + mi * 16 + (lane >> 4) * 4 + r;
                const int col = ncol0 + ni * 16 + (lane & 15);
                const int b = row / Tn, t = row % Tn;
                const float a = acc[mi][ni][r];
                if (col < 1536) {
                    const float val = a + bkkq[col];
                    const int third = col >> 9, nh = col & 511, n = nh >> 6, hh = nh & 63;
                    float* dst = (third == 0) ? k1 : (third == 1) ? k2 : qv;
                    dst[((b * NH + n) * Tn + t) * HD + hh] = val;
                } else if (col < 2048) {
                    const int c = col - 1536;
                    float val = a + bv1[c];
                    val = val / (1.f + __expf(-val));
                    sv1[((b * NH + (c >> 6)) * Tn + t) * HD + (c & 63)] = val;
                } else {
                    const int c = col - 2048;
                    v2o[((b * NH + (c >> 6)) * Tn + t) * HD + (c & 63)] = a + bv2[c];
                }
            }
}

// ---------------- Kernel 2: exp(score/64) tables ----------------
__global__ __launch_bounds__(256) void k_scores(
    const float* __restrict__ k1, const float* __restrict__ k2,
    const float* __restrict__ qv,
    float* __restrict__ Ekk, float* __restrict__ Eqk)
{
    const int bn  = blockIdx.z;
    const int mat = blockIdx.y;
    const int st  = blockIdx.x / 6, tt = blockIdx.x % 6;
    const float* A  = ((mat == 0) ? k1 : qv) + bn * Tn * HD;
    const float* Bm = k2 + bn * Tn * HD;
    float* E = ((mat == 0) ? Ekk : Eqk) + bn * TT;

    __shared__ float As[32][65], Bs[32][65];
    const int tid = threadIdx.x;
    for (int i = tid; i < 32 * 64; i += 256) {
        const int r = i >> 6, h = i & 63;
        As[r][h] = A[(st * 32 + r) * HD + h];
        Bs[r][h] = Bm[(tt * 32 + r) * HD + h];
    }
    __syncthreads();

    const int tx = tid & 15, ty = tid >> 4;
    const int r0 = ty * 2, c0 = tx * 2;
    float a00 = 0.f, a01 = 0.f, a10 = 0.f, a11 = 0.f;
#pragma unroll
    for (int h = 0; h < 64; ++h) {
        const float ar0 = As[r0][h], ar1 = As[r0 + 1][h];
        const float bc0 = Bs[c0][h], bc1 = Bs[c0 + 1][h];
        a00 = fmaf(ar0, bc0, a00); a01 = fmaf(ar0, bc1, a01);
        a10 = fmaf(ar1, bc0, a10); a11 = fmaf(ar1, bc1, a11);
    }
    constexpr float sc = 1.f / 64.f;
    const int gr = st * 32 + r0, gc = tt * 32 + c0;
    E[(gr)     * Tn + gc]     = __expf(a00 * sc);
    E[(gr)     * Tn + gc + 1] = __expf(a01 * sc);
    E[(gr + 1) * Tn + gc]     = __expf(a10 * sc);
    E[(gr + 1) * Tn + gc + 1] = __expf(a11 * sc);
}

// ---------------- Kernel 3a: per-chunk partial sums ----------------
__global__ __launch_bounds__(256) void k_partial(
    const float* __restrict__ Ekk, const float* __restrict__ sv1,
    float* __restrict__ P)
{
    const int hhalf = blockIdx.x;
    const int c     = blockIdx.y;
    const int bn    = blockIdx.z;
    const int tid   = threadIdx.x;
    const int tg    = tid & 7;
    const int h     = hhalf * 32 + (tid >> 3);
    const int t0    = tg * 24;
    const float* ekk = Ekk + bn * TT;
    const float* s1  = sv1 + bn * Tn * HD;

    float G[24];
#pragma unroll
    for (int j = 0; j < 24; ++j) G[j] = 0.f;

    for (int s = c * CS; s < c * CS + CS; ++s) {
        const float a = s1[s * HD + h];
        const float* ek = ekk + s * Tn + t0;
#pragma unroll
        for (int jj = 0; jj < 6; ++jj) {
            const float4 ev = *reinterpret_cast<const float4*>(&ek[4 * jj]);
            G[4*jj+0] = fmaf(ev.x, a, G[4*jj+0]);
            G[4*jj+1] = fmaf(ev.y, a, G[4*jj+1]);
            G[4*jj+2] = fmaf(ev.z, a, G[4*jj+2]);
            G[4*jj+3] = fmaf(ev.w, a, G[4*jj+3]);
        }
    }
    float* dst = P + ((bn * NC + c) * HD + h) * Tn + t0;
#pragma unroll
    for (int jj = 0; jj < 6; ++jj)
        *reinterpret_cast<float4*>(&dst[4 * jj]) =
            make_float4(G[4*jj], G[4*jj+1], G[4*jj+2], G[4*jj+3]);
}

// ---------------- Kernel 3b: inclusive scan over chunks ----------------
__global__ __launch_bounds__(256) void k_scan(float* __restrict__ P)
{
    const int bn  = blockIdx.y;
    const int off = blockIdx.x * 256 + threadIdx.x;
    float* base = P + bn * NC * HD * Tn;
    float run = base[off];
    for (int c = 1; c < NC; ++c) {
        run += base[c * HD * Tn + off];
        base[c * HD * Tn + off] = run;
    }
}

// ---------------- Kernel 3c: cumulative column sums of Ekk ----------------
__global__ __launch_bounds__(192) void k_gcum(
    const float* __restrict__ Ekk, float* __restrict__ gC)
{
    const int bn = blockIdx.x;
    const int t  = threadIdx.x;
    const float* ekk = Ekk + bn * TT;
    float sum = 0.f;
    for (int c = 0; c < NC; ++c) {
#pragma unroll
        for (int i = 0; i < CS; ++i)
            sum += ekk[(c * CS + i) * Tn + t];
        gC[(bn * NC + c) * Tn + t] = sum;
    }
}

// ---------------- Kernel 3d: attention from checkpoints ----------------
__global__ __launch_bounds__(256) void k_attn2(
    const float* __restrict__ Ekk, const float* __restrict__ Eqk,
    const float* __restrict__ sv1, const float* __restrict__ v2,
    const float* __restrict__ P,   const float* __restrict__ gC,
    bf16_t* __restrict__ zh, bf16_t* __restrict__ zl)
{
    const int hq = blockIdx.x;
    const int qt = blockIdx.y;
    const int bn = blockIdx.z;
    const int b = bn >> 3, n = bn & 7;
    const int tid = threadIdx.x;
    const int tg  = tid & 15;
    const int hh  = tid >> 4;
    const int h   = hq * 16 + hh;
    const int t0  = tg * 12;
    const int q0  = qt * 12;
    const int cb  = q0 / CS;

    const float* ekk = Ekk + bn * TT;
    const float* eqk = Eqk + bn * TT;
    const float* s1  = sv1 + bn * Tn * HD;
    const float* vv  = v2  + bn * Tn * HD;

    float G[12], g[12];
    if (cb > 0) {
        const float* pb = P  + ((bn * NC + (cb - 1)) * HD + h) * Tn + t0;
        const float* gb = gC + (bn * NC + (cb - 1)) * Tn + t0;
#pragma unroll
        for (int jj = 0; jj < 3; ++jj) {
            const float4 pv = *reinterpret_cast<const float4*>(&pb[4 * jj]);
            G[4*jj+0] = pv.x; G[4*jj+1] = pv.y; G[4*jj+2] = pv.z; G[4*jj+3] = pv.w;
            const float4 gv = *reinterpret_cast<const float4*>(&gb[4 * jj]);
            g[4*jj+0] = gv.x; g[4*jj+1] = gv.y; g[4*jj+2] = gv.z; g[4*jj+3] = gv.w;
        }
    } else {
#pragma unroll
        for (int j = 0; j < 12; ++j) { G[j] = 0.f; g[j] = 0.f; }
    }

    float vvr[12];
#pragma unroll
    for (int j = 0; j < 12; ++j) vvr[j] = vv[(t0 + j) * HD + h];

    for (int s = CS * cb; s < q0; ++s) {
        const float a = s1[s * HD + h];
        const float* ek = ekk + s * Tn + t0;
#pragma unroll
        for (int jj = 0; jj < 3; ++jj) {
            const float4 ev = *reinterpret_cast<const float4*>(&ek[4 * jj]);
            G[4*jj+0] = fmaf(ev.x, a, G[4*jj+0]); g[4*jj+0] += ev.x;
            G[4*jj+1] = fmaf(ev.y, a, G[4*jj+1]); g[4*jj+1] += ev.y;
            G[4*jj+2] = fmaf(ev.z, a, G[4*jj+2]); g[4*jj+2] += ev.z;
            G[4*jj+3] = fmaf(ev.w, a, G[4*jj+3]); g[4*jj+3] += ev.w;
        }
    }

    for (int q = q0; q < q0 + 12; ++q) {
        {
            const float a = s1[q * HD + h];
            const float* ek = ekk + q * Tn + t0;
#pragma unroll
            for (int jj = 0; jj < 3; ++jj) {
                const float4 ev = *reinterpret_cast<const float4*>(&ek[4 * jj]);
                G[4*jj+0] = fmaf(ev.x, a, G[4*jj+0]); g[4*jj+0] += ev.x;
                G[4*jj+1] = fmaf(ev.y, a, G[4*jj+1]); g[4*jj+1] += ev.y;
                G[4*jj+2] = fmaf(ev.z, a, G[4*jj+2]); g[4*jj+2] += ev.z;
                G[4*jj+3] = fmaf(ev.w, a, G[4*jj+3]); g[4*jj+3] += ev.w;
            }
        }
        const float* eq = eqk + q * Tn + t0;
        float zp = 0.f, Zp = 0.f;
#pragma unroll
        for (int jj = 0; jj < 3; ++jj) {
            const float4 ev = *reinterpret_cast<const float4*>(&eq[4 * jj]);
            const float e0 = (t0 + 4*jj + 0 <= q) ? ev.x : 0.f;
            const float e1 = (t0 + 4*jj + 1 <= q) ? ev.y : 0.f;
            const float e2 = (t0 + 4*jj + 2 <= q) ? ev.z : 0.f;
            const float e3 = (t0 + 4*jj + 3 <= q) ? ev.w : 0.f;
            zp = fmaf(e0 * vvr[4*jj+0], G[4*jj+0], zp); Zp = fmaf(e0, g[4*jj+0], Zp);
            zp = fmaf(e1 * vvr[4*jj+1], G[4*jj+1], zp); Zp = fmaf(e1, g[4*jj+1], Zp);
            zp = fmaf(e2 * vvr[4*jj+2], G[4*jj+2], zp); Zp = fmaf(e2, g[4*jj+2], Zp);
            zp = fmaf(e3 * vvr[4*jj+3], G[4*jj+3], zp); Zp = fmaf(e3, g[4*jj+3], Zp);
        }
        zp += __shfl_xor(zp, 1); zp += __shfl_xor(zp, 2);
        zp += __shfl_xor(zp, 4); zp += __shfl_xor(zp, 8);
        Zp += __shfl_xor(Zp, 1); Zp += __shfl_xor(Zp, 2);
        Zp += __shfl_xor(Zp, 4); Zp += __shfl_xor(Zp, 8);
        if (tg == 0) {
            const float r = zp / Zp;
            bf16pair p = split_bf16(r);
            const int idx = ((b * Tn + q) * NH + n) * HD + h;
            zh[idx] = p.h; zl[idx] = p.l;
        }
    }
}

// ---------------- Kernel 4: MFMA output projection ----------------
__global__ __launch_bounds__(256) void k_outm(
    const bf16_t* __restrict__ zh, const bf16_t* __restrict__ zl,
    const bf16_t* __restrict__ wouth, const bf16_t* __restrict__ woutl,
    const float* __restrict__ bout, float* __restrict__ out)
{
    const int bx = blockIdx.x, by = blockIdx.y;
    const int tid = threadIdx.x;
    const int w = tid >> 6, lane = tid & 63;
    const int wm = w >> 1, wn = w & 1;
    const int m0 = by * 64 + wm * 32;
    const int n0 = bx * 64 + wn * 32;
    const int lr = lane & 15, lk = (lane >> 4) * 8;

    const f32x4 z4 = {0.f, 0.f, 0.f, 0.f};
    f32x4 acc[2][2] = {{z4, z4}, {z4, z4}};

#pragma unroll 2
    for (int ks = 0; ks < 16; ++ks) {
        const int ko = ks * 32 + lk;
        bf16x8 ah[2], al[2], bh[2], bl[2];
#pragma unroll
        for (int mi = 0; mi < 2; ++mi) {
            const int row = m0 + mi * 16 + lr;
            ah[mi] = *reinterpret_cast<const bf16x8*>(&zh[row * DM + ko]);
            al[mi] = *reinterpret_cast<const bf16x8*>(&zl[row * DM + ko]);
        }
#pragma unroll
        for (int ni = 0; ni < 2; ++ni) {
            const int nrow = n0 + ni * 16 + lr;
            bh[ni] = *reinterpret_cast<const bf16x8*>(&wouth[nrow * DM + ko]);
            bl[ni] = *reinterpret_cast<const bf16x8*>(&woutl[nrow * DM + ko]);
        }
#pragma unroll
        for (int mi = 0; mi < 2; ++mi)
#pragma unroll
            for (int ni = 0; ni < 2; ++ni) {
                acc[mi][ni] = __builtin_amdgcn_mfma_f32_16x16x32_bf16(ah[mi], bh[ni], acc[mi][ni], 0, 0, 0);
                acc[mi][ni] = __builtin_amdgcn_mfma_f32_16x16x32_bf16(ah[mi], bl[ni], acc[mi][ni], 0, 0, 0);
                acc[mi][ni] = __builtin_amdgcn_mfma_f32_16x16x32_bf16(al[mi], bh[ni], acc[mi][ni], 0, 0, 0);
            }
    }

#pragma unroll
    for (int mi = 0; mi < 2; ++mi)
#pragma unroll
        for (int ni = 0; ni < 2; ++ni)
#pragma unroll
            for (int r = 0; r < 4; ++r) {
                const int row = m0 + mi * 16 + (lane >> 4) * 4 + r;
                const int col = n0 + ni * 16 + (lane & 15);
                out[row * DM + col] = acc[mi][ni][r] + bout[col];
            }
}

extern "C" void kernel_launch(void* const* d_in, const int* in_sizes, int n_in,
                              void* d_out, int out_size, void* d_ws, size_t ws_size,
                              hipStream_t stream) {
    const float* x    = (const float*)d_in[0];
    const float* Wkkq = (const float*)d_in[1];
    const float* bkkq = (const float*)d_in[2];
    const float* Wv1  = (const float*)d_in[3];
    const float* bv1  = (const float*)d_in[4];
    const float* Wv2  = (const float*)d_in[5];
    const float* bv2  = (const float*)d_in[6];
    const float* Wout = (const float*)d_in[7];
    const float* bout = (const float*)d_in[8];
    float* out = (float*)d_out;

    // float region
    float* ws  = (float*)d_ws;
    float* k1  = ws;
    float* k2  = k1  + 196608;
    float* qv  = k2  + 196608;
    float* sv1 = qv  + 196608;
    float* v2  = sv1 + 196608;
    float* Ekk = v2  + 196608;
    float* Eqk = Ekk + 589824;
    float* P   = Eqk + 589824;
    float* gC  = P   + 1572864;
    // bf16 region
    bf16_t* bws   = (bf16_t*)(gC + 24576);
    bf16_t* xh    = bws;
    bf16_t* xl    = xh    + 196608;
    bf16_t* zh    = xl    + 196608;
    bf16_t* zl    = zh    + 196608;
    bf16_t* wkkqh = zl    + 196608;
    bf16_t* wkkql = wkkqh + 786432;
    bf16_t* wv1h  = wkkql + 786432;
    bf16_t* wv1l  = wv1h  + 262144;
    bf16_t* wv2h  = wv1l  + 262144;
    bf16_t* wv2l  = wv2h  + 262144;
    bf16_t* wouth = wv2l  + 262144;
    bf16_t* woutl = wouth + 262144;

    k_convert<<<dim3(1728),      256, 0, stream>>>(x, Wkkq, Wv1, Wv2, Wout,
                                                   xh, xl, wkkqh, wkkql,
                                                   wv1h, wv1l, wv2h, wv2l, wouth, woutl);
    k_projm  <<<dim3(40, 6),     256, 0, stream>>>(xh, xl, wkkqh, wkkql, wv1h, wv1l,
                                                   wv2h, wv2l, bkkq, bv1, bv2,
                                                   k1, k2, qv, sv1, v2);
    k_scores <<<dim3(36, 2, 16), 256, 0, stream>>>(k1, k2, qv, Ekk, Eqk);
    k_partial<<<dim3(2, 8, 16),  256, 0, stream>>>(Ekk, sv1, P);
    k_gcum   <<<dim3(16),        192, 0, stream>>>(Ekk, gC);
    k_scan   <<<dim3(48, 16),    256, 0, stream>>>(P);
    k_attn2  <<<dim3(4, 16, 16), 256, 0, stream>>>(Ekk, Eqk, sv1, v2, P, gC, zh, zl);
    k_outm   <<<dim3(8, 6),      256, 0, stream>>>(zh, zl, wouth, woutl, bout, out);
}

// Round 6
// 98.491 us; speedup vs baseline: 3.4813x; 1.1023x over previous
//
#include <hip/hip_runtime.h>
#include <hip/hip_bf16.h>

// Trittention, factorized:
//   z[q,h] = sum_{t<=q} Eqk[q,t]*v2[t,h]*G_q[t,h] / sum_{t<=q} Eqk[q,t]*g_q[t]
//   G_q[t,h] = sum_{s<=q} Ekk[s,t]*silu(v1)[s,h]   (prefix over s)
// R5: MFMA GEMMs restructured for latency: more blocks (32x64 / 16x64 tiles),
// register double-buffered K-loop (1-deep prefetch), z kept fp32 (in-reg split
// in k_outm), gcum merged into scan. bf16x3 split: A.B ~ Ah.Bh + Ah.Bl + Al.Bh.

constexpr int Tn = 192;
constexpr int DM = 512;
constexpr int NH = 8;
constexpr int HD = 64;
constexpr int TT = Tn * Tn;
constexpr int NC = 8;            // checkpoint chunks
constexpr int CS = 24;           // s-rows per chunk

typedef __bf16 bf16_t;
typedef bf16_t bf16x8 __attribute__((ext_vector_type(8)));
typedef bf16_t bf16x4 __attribute__((ext_vector_type(4)));
typedef float  f32x4  __attribute__((ext_vector_type(4)));

struct bf16pair { bf16_t h, l; };
__device__ __forceinline__ bf16pair split_bf16(float v) {
    bf16pair r;
    r.h = (bf16_t)v;
    r.l = (bf16_t)(v - (float)r.h);
    return r;
}

// ---------------- Kernel 0: convert x + transpose-convert weights ----------
// Weights W[K][N] fp32 -> Wt_hi/Wt_lo [N][K=512] bf16. x -> xhi/xlo bf16.
__global__ __launch_bounds__(256) void k_convert(
    const float* __restrict__ x,    const float* __restrict__ Wkkq,
    const float* __restrict__ Wv1,  const float* __restrict__ Wv2,
    const float* __restrict__ Wout,
    bf16_t* __restrict__ xh,    bf16_t* __restrict__ xl,
    bf16_t* __restrict__ wkkqh, bf16_t* __restrict__ wkkql,
    bf16_t* __restrict__ wv1h,  bf16_t* __restrict__ wv1l,
    bf16_t* __restrict__ wv2h,  bf16_t* __restrict__ wv2l,
    bf16_t* __restrict__ wouth, bf16_t* __restrict__ woutl)
{
    const int bid = blockIdx.x;
    const int tid = threadIdx.x;

    if (bid >= 1536) {   // x path: elementwise convert
        const int idx = (bid - 1536) * 1024 + tid * 4;
        const float4 v = *reinterpret_cast<const float4*>(&x[idx]);
        bf16x4 hv, lv;
        bf16pair p0 = split_bf16(v.x), p1 = split_bf16(v.y);
        bf16pair p2 = split_bf16(v.z), p3 = split_bf16(v.w);
        hv[0] = p0.h; lv[0] = p0.l; hv[1] = p1.h; lv[1] = p1.l;
        hv[2] = p2.h; lv[2] = p2.l; hv[3] = p3.h; lv[3] = p3.l;
        *reinterpret_cast<bf16x4*>(&xh[idx]) = hv;
        *reinterpret_cast<bf16x4*>(&xl[idx]) = lv;
        return;
    }

    const float* src; bf16_t* dh; bf16_t* dl; int N, lb;
    if (bid < 768)       { src = Wkkq; dh = wkkqh; dl = wkkql; N = 1536; lb = bid; }
    else if (bid < 1024) { src = Wv1;  dh = wv1h;  dl = wv1l;  N = 512;  lb = bid - 768; }
    else if (bid < 1280) { src = Wv2;  dh = wv2h;  dl = wv2l;  N = 512;  lb = bid - 1024; }
    else                 { src = Wout; dh = wouth; dl = woutl; N = 512;  lb = bid - 1280; }

    const int ntn = N >> 5;
    const int k0 = (lb / ntn) * 32, n0 = (lb % ntn) * 32;

    __shared__ float T[32][33];
    const int r = tid >> 3, c4 = (tid & 7) * 4;
    const float4 v = *reinterpret_cast<const float4*>(&src[(k0 + r) * N + n0 + c4]);
    T[r][c4] = v.x; T[r][c4 + 1] = v.y; T[r][c4 + 2] = v.z; T[r][c4 + 3] = v.w;
    __syncthreads();

    const int nr = tid >> 3, kc4 = (tid & 7) * 4;
    bf16x4 hv, lv;
#pragma unroll
    for (int i = 0; i < 4; ++i) {
        bf16pair p = split_bf16(T[kc4 + i][nr]);
        hv[i] = p.h; lv[i] = p.l;
    }
    *reinterpret_cast<bf16x4*>(&dh[(n0 + nr) * DM + k0 + kc4]) = hv;
    *reinterpret_cast<bf16x4*>(&dl[(n0 + nr) * DM + k0 + kc4]) = lv;
}

// ---------------- Kernel 1: MFMA projection GEMM ----------------
// [384x512] @ [512x2560]; 32x64 tile, 4 waves (wave = 16x32), reg dbuf K-loop.
__global__ __launch_bounds__(256) void k_projm(
    const bf16_t* __restrict__ xh,    const bf16_t* __restrict__ xl,
    const bf16_t* __restrict__ wkkqh, const bf16_t* __restrict__ wkkql,
    const bf16_t* __restrict__ wv1h,  const bf16_t* __restrict__ wv1l,
    const bf16_t* __restrict__ wv2h,  const bf16_t* __restrict__ wv2l,
    const float* __restrict__ bkkq, const float* __restrict__ bv1,
    const float* __restrict__ bv2,
    float* __restrict__ k1, float* __restrict__ k2, float* __restrict__ qv,
    float* __restrict__ sv1, float* __restrict__ v2o)
{
    const int bx = blockIdx.x, by = blockIdx.y;   // bx: 40 col-tiles, by: 12 row-tiles
    const int tid = threadIdx.x;
    const int w = tid >> 6, lane = tid & 63;
    const int wm = w & 1, wn = w >> 1;            // row half (16), col half (32)
    const int lr = lane & 15, lk = (lane >> 4) * 8;

    const bf16_t *Bh, *Bl; int nbase;             // segment-local col base
    if (bx < 24)      { Bh = wkkqh; Bl = wkkql; nbase = bx * 64; }
    else if (bx < 32) { Bh = wv1h;  Bl = wv1l;  nbase = bx * 64 - 1536; }
    else              { Bh = wv2h;  Bl = wv2l;  nbase = bx * 64 - 2048; }

    const int arow  = by * 32 + wm * 16 + lr;
    const int brow0 = nbase + wn * 32 + lr;
    const int brow1 = brow0 + 16;

    f32x4 acc0 = {0.f,0.f,0.f,0.f}, acc1 = {0.f,0.f,0.f,0.f};
    bf16x8 A_ah, A_al, A_b0h, A_b0l, A_b1h, A_b1l;
    bf16x8 B_ah, B_al, B_b0h, B_b0l, B_b1h, B_b1l;

#define PLD(P_, KS) do { const int ko_ = (KS) * 32 + lk;                     \
    P_##ah  = *reinterpret_cast<const bf16x8*>(&xh[arow  * DM + ko_]);       \
    P_##al  = *reinterpret_cast<const bf16x8*>(&xl[arow  * DM + ko_]);       \
    P_##b0h = *reinterpret_cast<const bf16x8*>(&Bh[brow0 * DM + ko_]);       \
    P_##b0l = *reinterpret_cast<const bf16x8*>(&Bl[brow0 * DM + ko_]);       \
    P_##b1h = *reinterpret_cast<const bf16x8*>(&Bh[brow1 * DM + ko_]);       \
    P_##b1l = *reinterpret_cast<const bf16x8*>(&Bl[brow1 * DM + ko_]); } while (0)
#define PMM(P_) do {                                                                      \
    acc0 = __builtin_amdgcn_mfma_f32_16x16x32_bf16(P_##ah, P_##b0h, acc0, 0, 0, 0);       \
    acc0 = __builtin_amdgcn_mfma_f32_16x16x32_bf16(P_##ah, P_##b0l, acc0, 0, 0, 0);       \
    acc0 = __builtin_amdgcn_mfma_f32_16x16x32_bf16(P_##al, P_##b0h, acc0, 0, 0, 0);       \
    acc1 = __builtin_amdgcn_mfma_f32_16x16x32_bf16(P_##ah, P_##b1h, acc1, 0, 0, 0);       \
    acc1 = __builtin_amdgcn_mfma_f32_16x16x32_bf16(P_##ah, P_##b1l, acc1, 0, 0, 0);       \
    acc1 = __builtin_amdgcn_mfma_f32_16x16x32_bf16(P_##al, P_##b1h, acc1, 0, 0, 0); } while (0)

    PLD(A_, 0);
    for (int ks = 0; ks < 14; ks += 2) {
        PLD(B_, ks + 1);
        PMM(A_);
        PLD(A_, ks + 2);
        PMM(B_);
    }
    PLD(B_, 15);
    PMM(A_);
    PMM(B_);
#undef PLD
#undef PMM

#pragma unroll
    for (int ni = 0; ni < 2; ++ni) {
        const f32x4 a4 = ni ? acc1 : acc0;
        const int gcol = bx * 64 + wn * 32 + ni * 16 + lr;
#pragma unroll
        for (int r = 0; r < 4; ++r) {
            const int row = by * 32 + wm * 16 + (lane >> 4) * 4 + r;
            const int b = row / Tn, t = row % Tn;
            const float a = a4[r];
            if (gcol < 1536) {
                const float val = a + bkkq[gcol];
                const int third = gcol >> 9, nh = gcol & 511, n = nh >> 6, hh = nh & 63;
                float* dst = (third == 0) ? k1 : (third == 1) ? k2 : qv;
                dst[((b * NH + n) * Tn + t) * HD + hh] = val;
            } else if (gcol < 2048) {
                const int c = gcol - 1536;
                float val = a + bv1[c];
                val = val / (1.f + __expf(-val));
                sv1[((b * NH + (c >> 6)) * Tn + t) * HD + (c & 63)] = val;
            } else {
                const int c = gcol - 2048;
                v2o[((b * NH + (c >> 6)) * Tn + t) * HD + (c & 63)] = a + bv2[c];
            }
        }
    }
}

// ---------------- Kernel 2: exp(score/64) tables ----------------
__global__ __launch_bounds__(256) void k_scores(
    const float* __restrict__ k1, const float* __restrict__ k2,
    const float* __restrict__ qv,
    float* __restrict__ Ekk, float* __restrict__ Eqk)
{
    const int bn  = blockIdx.z;
    const int mat = blockIdx.y;
    const int st  = blockIdx.x / 6, tt = blockIdx.x % 6;
    const float* A  = ((mat == 0) ? k1 : qv) + bn * Tn * HD;
    const float* Bm = k2 + bn * Tn * HD;
    float* E = ((mat == 0) ? Ekk : Eqk) + bn * TT;

    __shared__ float As[32][65], Bs[32][65];
    const int tid = threadIdx.x;
    for (int i = tid; i < 32 * 64; i += 256) {
        const int r = i >> 6, h = i & 63;
        As[r][h] = A[(st * 32 + r) * HD + h];
        Bs[r][h] = Bm[(tt * 32 + r) * HD + h];
    }
    __syncthreads();

    const int tx = tid & 15, ty = tid >> 4;
    const int r0 = ty * 2, c0 = tx * 2;
    float a00 = 0.f, a01 = 0.f, a10 = 0.f, a11 = 0.f;
#pragma unroll
    for (int h = 0; h < 64; ++h) {
        const float ar0 = As[r0][h], ar1 = As[r0 + 1][h];
        const float bc0 = Bs[c0][h], bc1 = Bs[c0 + 1][h];
        a00 = fmaf(ar0, bc0, a00); a01 = fmaf(ar0, bc1, a01);
        a10 = fmaf(ar1, bc0, a10); a11 = fmaf(ar1, bc1, a11);
    }
    constexpr float sc = 1.f / 64.f;
    const int gr = st * 32 + r0, gc = tt * 32 + c0;
    E[(gr)     * Tn + gc]     = __expf(a00 * sc);
    E[(gr)     * Tn + gc + 1] = __expf(a01 * sc);
    E[(gr + 1) * Tn + gc]     = __expf(a10 * sc);
    E[(gr + 1) * Tn + gc + 1] = __expf(a11 * sc);
}

// ---------------- Kernel 3a: per-chunk partial sums ----------------
__global__ __launch_bounds__(256) void k_partial(
    const float* __restrict__ Ekk, const float* __restrict__ sv1,
    float* __restrict__ P)
{
    const int hhalf = blockIdx.x;
    const int c     = blockIdx.y;
    const int bn    = blockIdx.z;
    const int tid   = threadIdx.x;
    const int tg    = tid & 7;
    const int h     = hhalf * 32 + (tid >> 3);
    const int t0    = tg * 24;
    const float* ekk = Ekk + bn * TT;
    const float* s1  = sv1 + bn * Tn * HD;

    float G[24];
#pragma unroll
    for (int j = 0; j < 24; ++j) G[j] = 0.f;

    for (int s = c * CS; s < c * CS + CS; ++s) {
        const float a = s1[s * HD + h];
        const float* ek = ekk + s * Tn + t0;
#pragma unroll
        for (int jj = 0; jj < 6; ++jj) {
            const float4 ev = *reinterpret_cast<const float4*>(&ek[4 * jj]);
            G[4*jj+0] = fmaf(ev.x, a, G[4*jj+0]);
            G[4*jj+1] = fmaf(ev.y, a, G[4*jj+1]);
            G[4*jj+2] = fmaf(ev.z, a, G[4*jj+2]);
            G[4*jj+3] = fmaf(ev.w, a, G[4*jj+3]);
        }
    }
    float* dst = P + ((bn * NC + c) * HD + h) * Tn + t0;
#pragma unroll
    for (int jj = 0; jj < 6; ++jj)
        *reinterpret_cast<float4*>(&dst[4 * jj]) =
            make_float4(G[4*jj], G[4*jj+1], G[4*jj+2], G[4*jj+3]);
}

// ---------------- Kernel 3b: scan over chunks + gcum (fused) ----------------
__global__ __launch_bounds__(256) void k_scangc(
    float* __restrict__ P, const float* __restrict__ Ekk, float* __restrict__ gC)
{
    const int bn = blockIdx.y;
    if (blockIdx.x < 48) {
        const int off = blockIdx.x * 256 + threadIdx.x;
        float* base = P + bn * NC * HD * Tn;
        float run = base[off];
        for (int c = 1; c < NC; ++c) {
            run += base[c * HD * Tn + off];
            base[c * HD * Tn + off] = run;
        }
    } else {
        const int t = threadIdx.x;
        if (t < Tn) {
            const float* ekk = Ekk + bn * TT;
            float sum = 0.f;
            for (int c = 0; c < NC; ++c) {
#pragma unroll
                for (int i = 0; i < CS; ++i)
                    sum += ekk[(c * CS + i) * Tn + t];
                gC[(bn * NC + c) * Tn + t] = sum;
            }
        }
    }
}

// ---------------- Kernel 3d: attention from checkpoints ----------------
__global__ __launch_bounds__(256) void k_attn2(
    const float* __restrict__ Ekk, const float* __restrict__ Eqk,
    const float* __restrict__ sv1, const float* __restrict__ v2,
    const float* __restrict__ P,   const float* __restrict__ gC,
    float* __restrict__ z)
{
    const int hq = blockIdx.x;
    const int qt = blockIdx.y;
    const int bn = blockIdx.z;
    const int b = bn >> 3, n = bn & 7;
    const int tid = threadIdx.x;
    const int tg  = tid & 15;
    const int hh  = tid >> 4;
    const int h   = hq * 16 + hh;
    const int t0  = tg * 12;
    const int q0  = qt * 12;
    const int cb  = q0 / CS;

    const float* ekk = Ekk + bn * TT;
    const float* eqk = Eqk + bn * TT;
    const float* s1  = sv1 + bn * Tn * HD;
    const float* vv  = v2  + bn * Tn * HD;

    float G[12], g[12];
    if (cb > 0) {
        const float* pb = P  + ((bn * NC + (cb - 1)) * HD + h) * Tn + t0;
        const float* gb = gC + (bn * NC + (cb - 1)) * Tn + t0;
#pragma unroll
        for (int jj = 0; jj < 3; ++jj) {
            const float4 pv = *reinterpret_cast<const float4*>(&pb[4 * jj]);
            G[4*jj+0] = pv.x; G[4*jj+1] = pv.y; G[4*jj+2] = pv.z; G[4*jj+3] = pv.w;
            const float4 gv = *reinterpret_cast<const float4*>(&gb[4 * jj]);
            g[4*jj+0] = gv.x; g[4*jj+1] = gv.y; g[4*jj+2] = gv.z; g[4*jj+3] = gv.w;
        }
    } else {
#pragma unroll
        for (int j = 0; j < 12; ++j) { G[j] = 0.f; g[j] = 0.f; }
    }

    float vvr[12];
#pragma unroll
    for (int j = 0; j < 12; ++j) vvr[j] = vv[(t0 + j) * HD + h];

    for (int s = CS * cb; s < q0; ++s) {
        const float a = s1[s * HD + h];
        const float* ek = ekk + s * Tn + t0;
#pragma unroll
        for (int jj = 0; jj < 3; ++jj) {
            const float4 ev = *reinterpret_cast<const float4*>(&ek[4 * jj]);
            G[4*jj+0] = fmaf(ev.x, a, G[4*jj+0]); g[4*jj+0] += ev.x;
            G[4*jj+1] = fmaf(ev.y, a, G[4*jj+1]); g[4*jj+1] += ev.y;
            G[4*jj+2] = fmaf(ev.z, a, G[4*jj+2]); g[4*jj+2] += ev.z;
            G[4*jj+3] = fmaf(ev.w, a, G[4*jj+3]); g[4*jj+3] += ev.w;
        }
    }

    for (int q = q0; q < q0 + 12; ++q) {
        {
            const float a = s1[q * HD + h];
            const float* ek = ekk + q * Tn + t0;
#pragma unroll
            for (int jj = 0; jj < 3; ++jj) {
                const float4 ev = *reinterpret_cast<const float4*>(&ek[4 * jj]);
                G[4*jj+0] = fmaf(ev.x, a, G[4*jj+0]); g[4*jj+0] += ev.x;
                G[4*jj+1] = fmaf(ev.y, a, G[4*jj+1]); g[4*jj+1] += ev.y;
                G[4*jj+2] = fmaf(ev.z, a, G[4*jj+2]); g[4*jj+2] += ev.z;
                G[4*jj+3] = fmaf(ev.w, a, G[4*jj+3]); g[4*jj+3] += ev.w;
            }
        }
        const float* eq = eqk + q * Tn + t0;
        float zp = 0.f, Zp = 0.f;
#pragma unroll
        for (int jj = 0; jj < 3; ++jj) {
            const float4 ev = *reinterpret_cast<const float4*>(&eq[4 * jj]);
            const float e0 = (t0 + 4*jj + 0 <= q) ? ev.x : 0.f;
            const float e1 = (t0 + 4*jj + 1 <= q) ? ev.y : 0.f;
            const float e2 = (t0 + 4*jj + 2 <= q) ? ev.z : 0.f;
            const float e3 = (t0 + 4*jj + 3 <= q) ? ev.w : 0.f;
            zp = fmaf(e0 * vvr[4*jj+0], G[4*jj+0], zp); Zp = fmaf(e0, g[4*jj+0], Zp);
            zp = fmaf(e1 * vvr[4*jj+1], G[4*jj+1], zp); Zp = fmaf(e1, g[4*jj+1], Zp);
            zp = fmaf(e2 * vvr[4*jj+2], G[4*jj+2], zp); Zp = fmaf(e2, g[4*jj+2], Zp);
            zp = fmaf(e3 * vvr[4*jj+3], G[4*jj+3], zp); Zp = fmaf(e3, g[4*jj+3], Zp);
        }
        zp += __shfl_xor(zp, 1); zp += __shfl_xor(zp, 2);
        zp += __shfl_xor(zp, 4); zp += __shfl_xor(zp, 8);
        Zp += __shfl_xor(Zp, 1); Zp += __shfl_xor(Zp, 2);
        Zp += __shfl_xor(Zp, 4); Zp += __shfl_xor(Zp, 8);
        if (tg == 0) z[((b * Tn + q) * NH + n) * HD + h] = zp / Zp;
    }
}

// ---------------- Kernel 4: MFMA output projection ----------------
// [384x512] @ [512x512]; 16x64 tile, 4 waves (wave = 16x16), reg dbuf K-loop,
// A split fp32->bf16 hi/lo in-register.
__global__ __launch_bounds__(256) void k_outm(
    const float* __restrict__ z,
    const bf16_t* __restrict__ wouth, const bf16_t* __restrict__ woutl,
    const float* __restrict__ bout, float* __restrict__ out)
{
    const int bx = blockIdx.x, by = blockIdx.y;   // bx: 8 col-tiles, by: 24 row-tiles
    const int tid = threadIdx.x;
    const int w = tid >> 6, lane = tid & 63;
    const int lr = lane & 15, lk = (lane >> 4) * 8;
    const int arow = by * 16 + lr;
    const int brow = bx * 64 + w * 16 + lr;

    f32x4 acc = {0.f,0.f,0.f,0.f};
    bf16x8 A_ah, A_al, A_bh, A_bl;
    bf16x8 B_ah, B_al, B_bh, B_bl;

#define OLD(P_, KS) do { const int ko_ = (KS) * 32 + lk;                       \
    const float4 u0 = *reinterpret_cast<const float4*>(&z[arow * DM + ko_]);   \
    const float4 u1 = *reinterpret_cast<const float4*>(&z[arow * DM + ko_ + 4]); \
    bf16pair q0 = split_bf16(u0.x), q1 = split_bf16(u0.y);                     \
    bf16pair q2 = split_bf16(u0.z), q3 = split_bf16(u0.w);                     \
    bf16pair q4 = split_bf16(u1.x), q5 = split_bf16(u1.y);                     \
    bf16pair q6 = split_bf16(u1.z), q7 = split_bf16(u1.w);                     \
    P_##ah[0] = q0.h; P_##al[0] = q0.l; P_##ah[1] = q1.h; P_##al[1] = q1.l;    \
    P_##ah[2] = q2.h; P_##al[2] = q2.l; P_##ah[3] = q3.h; P_##al[3] = q3.l;    \
    P_##ah[4] = q4.h; P_##al[4] = q4.l; P_##ah[5] = q5.h; P_##al[5] = q5.l;    \
    P_##ah[6] = q6.h; P_##al[6] = q6.l; P_##ah[7] = q7.h; P_##al[7] = q7.l;    \
    P_##bh = *reinterpret_cast<const bf16x8*>(&wouth[brow * DM + ko_]);        \
    P_##bl = *reinterpret_cast<const bf16x8*>(&woutl[brow * DM + ko_]); } while (0)
#define OMM(P_) do {                                                                   \
    acc = __builtin_amdgcn_mfma_f32_16x16x32_bf16(P_##ah, P_##bh, acc, 0, 0, 0);       \
    acc = __builtin_amdgcn_mfma_f32_16x16x32_bf16(P_##ah, P_##bl, acc, 0, 0, 0);       \
    acc = __builtin_amdgcn_mfma_f32_16x16x32_bf16(P_##al, P_##bh, acc, 0, 0, 0); } while (0)

    OLD(A_, 0);
    for (int ks = 0; ks < 14; ks += 2) {
        OLD(B_, ks + 1);
        OMM(A_);
        OLD(A_, ks + 2);
        OMM(B_);
    }
    OLD(B_, 15);
    OMM(A_);
    OMM(B_);
#undef OLD
#undef OMM

    const int col = bx * 64 + w * 16 + lr;
#pragma unroll
    for (int r = 0; r < 4; ++r) {
        const int row = by * 16 + (lane >> 4) * 4 + r;
        out[row * DM + col] = acc[r] + bout[col];
    }
}

extern "C" void kernel_launch(void* const* d_in, const int* in_sizes, int n_in,
                              void* d_out, int out_size, void* d_ws, size_t ws_size,
                              hipStream_t stream) {
    const float* x    = (const float*)d_in[0];
    const float* Wkkq = (const float*)d_in[1];
    const float* bkkq = (const float*)d_in[2];
    const float* Wv1  = (const float*)d_in[3];
    const float* bv1  = (const float*)d_in[4];
    const float* Wv2  = (const float*)d_in[5];
    const float* bv2  = (const float*)d_in[6];
    const float* Wout = (const float*)d_in[7];
    const float* bout = (const float*)d_in[8];
    float* out = (float*)d_out;

    // float region
    float* ws  = (float*)d_ws;
    float* k1  = ws;
    float* k2  = k1  + 196608;
    float* qv  = k2  + 196608;
    float* sv1 = qv  + 196608;
    float* v2  = sv1 + 196608;
    float* z   = v2  + 196608;
    float* Ekk = z   + 196608;
    float* Eqk = Ekk + 589824;
    float* P   = Eqk + 589824;
    float* gC  = P   + 1572864;
    // bf16 region
    bf16_t* bws   = (bf16_t*)(gC + 24576);
    bf16_t* xh    = bws;
    bf16_t* xl    = xh    + 196608;
    bf16_t* wkkqh = xl    + 196608;
    bf16_t* wkkql = wkkqh + 786432;
    bf16_t* wv1h  = wkkql + 786432;
    bf16_t* wv1l  = wv1h  + 262144;
    bf16_t* wv2h  = wv1l  + 262144;
    bf16_t* wv2l  = wv2h  + 262144;
    bf16_t* wouth = wv2l  + 262144;
    bf16_t* woutl = wouth + 262144;

    k_convert<<<dim3(1728),      256, 0, stream>>>(x, Wkkq, Wv1, Wv2, Wout,
                                                   xh, xl, wkkqh, wkkql,
                                                   wv1h, wv1l, wv2h, wv2l, wouth, woutl);
    k_projm  <<<dim3(40, 12),    256, 0, stream>>>(xh, xl, wkkqh, wkkql, wv1h, wv1l,
                                                   wv2h, wv2l, bkkq, bv1, bv2,
                                                   k1, k2, qv, sv1, v2);
    k_scores <<<dim3(36, 2, 16), 256, 0, stream>>>(k1, k2, qv, Ekk, Eqk);
    k_partial<<<dim3(2, 8, 16),  256, 0, stream>>>(Ekk, sv1, P);
    k_scangc <<<dim3(49, 16),    256, 0, stream>>>(P, Ekk, gC);
    k_attn2  <<<dim3(4, 16, 16), 256, 0, stream>>>(Ekk, Eqk, sv1, v2, P, gC, z);
    k_outm   <<<dim3(8, 24),     256, 0, stream>>>(z, wouth, woutl, bout, out);
}